// Round 3
// baseline (253.862 us; speedup 1.0000x reference)
//
#include <hip/hip_runtime.h>
#include <stdint.h>

#define NB 16
#define NC 256
#define NH 48
#define NW 64
#define ND 21
#define HW (NH * NW)
#define ROW_ELEMS (NW * NC)  // one (b,y) row as [x][c] bf16: 16384 elems = 32KB

typedef __bf16 bf16x8 __attribute__((ext_vector_type(8)));
typedef float f32x4 __attribute__((ext_vector_type(4)));

// row layout: [x][c] bf16, c in 16B chunks of 8; low-3 chunk bits XOR (x&7).
// 512B per x. ds_read_b128 / ds_write_b128 on this layout are conflict-free.
__device__ __forceinline__ int sw_addr(int x, int chunk) {
    int cs = (chunk & ~7) | ((chunk ^ x) & 7);
    return x * 256 + (cs << 3);
}

// read 8 consecutive c (coalesced across x-lanes) -> packed bf16x8
__device__ __forceinline__ bf16x8 load_pack8(const float* __restrict__ p, int cbase) {
    bf16x8 v;
#pragma unroll
    for (int j = 0; j < 8; ++j)
        v[j] = (__bf16)p[(size_t)(cbase + j) * HW];
    return v;
}

// ---------- pre-pass: in2 fp32 [b][c][h][w] -> ws bf16 rows (swizzle baked) --
__global__ void __launch_bounds__(256, 4)
convert_in2(const float* __restrict__ in2, unsigned short* __restrict__ ws) {
    __shared__ unsigned short s[ROW_ELEMS];
    const int tid = threadIdx.x;
    const int b = blockIdx.x / NH, y = blockIdx.x % NH;
    const int x = tid & 63, g0 = tid >> 6;
    const float* p = in2 + ((size_t)b * NC * NH + y) * NW + x;
#pragma unroll
    for (int i = 0; i < 8; ++i) {
        const int chunk = g0 * 8 + i;                  // c = chunk*8 .. +7
        bf16x8 v = load_pack8(p, chunk * 8);
        *(bf16x8*)&s[sw_addr(x, chunk)] = v;           // b128, conflict-free
    }
    __syncthreads();
    unsigned short* wr = ws + ((size_t)b * NH + y) * ROW_ELEMS;
#pragma unroll
    for (int i = 0; i < 8; ++i) {
        const int e = (i * 256 + tid) * 8;
        *(bf16x8*)(wr + e) = *(const bf16x8*)(s + e);  // linear, coalesced
    }
}

// ---------- main: block per (b,y); wave = M64 x N16; B direct from global ---
__global__ void __launch_bounds__(256, 2)
corr_main(const float* __restrict__ in1, const unsigned short* __restrict__ ws,
          float* __restrict__ out) {
    __shared__ unsigned short s1[ROW_ELEMS];  // 32KB, in1 row, never recycled
    const int tid  = threadIdx.x;
    const int b    = blockIdx.x / NH, y = blockIdx.x % NH;
    const int lane = tid & 63, wave = tid >> 6;
    const int m_lo = lane & 15, quad = lane >> 4;

    // ---- stage in1 row (register-packed, conflict-free b128 writes)
    {
        const int x = tid & 63, g0 = tid >> 6;
        const float* p = in1 + ((size_t)b * NC * NH + y) * NW + x;
#pragma unroll
        for (int i = 0; i < 8; ++i) {
            const int chunk = g0 * 8 + i;
            bf16x8 v = load_pack8(p, chunk * 8);
            *(bf16x8*)&s1[sw_addr(x, chunk)] = v;
        }
    }
    __syncthreads();

    // ---- cache A for all 4 M-tiles: A[m=lane&15][k=quad*8+j]
    bf16x8 afrag[4][8];
#pragma unroll
    for (int mm = 0; mm < 4; ++mm) {
        const int x = 16 * mm + m_lo;
#pragma unroll
        for (int kb = 0; kb < 8; ++kb)
            afrag[mm][kb] = *(const bf16x8*)&s1[sw_addr(x, 4 * kb + quad)];
    }

    // ---- zero invalid dy planes
    const int d0 = (y >= 20) ? 0 : (21 - y) >> 1;
    const int d1 = min(20, (67 - y) >> 1);
    float* outbase = out + (((size_t)b * (ND * ND)) * NH + (size_t)y) * NW;
    for (int dyi = 0; dyi < ND; ++dyi) {
        if (dyi >= d0 && dyi <= d1) continue;
        float* ob = outbase + (size_t)dyi * ND * HW;
        for (int i = tid; i < ND * NW; i += 256)
            ob[(size_t)(i >> 6) * HW + (i & 63)] = 0.0f;
    }

    const unsigned short* wsb = ws + (size_t)b * NH * ROW_ELEMS;
    const float scale = 1.0f / 256.0f;
    const int xp = 16 * wave + m_lo;  // this lane's B column (x')

    // ---- dy loop: NO barriers, B-frags straight from global (L2/L3-hot)
    for (int dyi = d0; dyi <= d1; ++dyi) {
        const unsigned short* row = wsb + (size_t)(y - 20 + 2 * dyi) * ROW_ELEMS;

        bf16x8 bfrag[8];
#pragma unroll
        for (int kb = 0; kb < 8; ++kb)
            bfrag[kb] = *(const bf16x8*)&row[sw_addr(xp, 4 * kb + quad)];

        f32x4 acc[4];
#pragma unroll
        for (int mm = 0; mm < 4; ++mm) acc[mm] = (f32x4){0.f, 0.f, 0.f, 0.f};
#pragma unroll
        for (int kb = 0; kb < 8; ++kb) {
            acc[0] = __builtin_amdgcn_mfma_f32_16x16x32_bf16(afrag[0][kb], bfrag[kb], acc[0], 0, 0, 0);
            acc[1] = __builtin_amdgcn_mfma_f32_16x16x32_bf16(afrag[1][kb], bfrag[kb], acc[1], 0, 0, 0);
            acc[2] = __builtin_amdgcn_mfma_f32_16x16x32_bf16(afrag[2][kb], bfrag[kb], acc[2], 0, 0, 0);
            acc[3] = __builtin_amdgcn_mfma_f32_16x16x32_bf16(afrag[3][kb], bfrag[kb], acc[3], 0, 0, 0);
        }

        // ---- band extraction: row index = 16*mm + 4*quad + r (=x), col = xp
        float* ob = outbase + (size_t)dyi * ND * HW;
#pragma unroll
        for (int mm = 0; mm < 4; ++mm) {
            const int xb = 16 * mm + 4 * quad;
#pragma unroll
            for (int r = 0; r < 4; ++r) {
                const int x = xb + r;
                const int d = xp - x;
                if (d >= -20 && d <= 20 && !(d & 1))
                    ob[(size_t)((d + 20) >> 1) * HW + x] = acc[mm][r] * scale;
            }
        }
        // ---- zero-fill x where x+dx out of [0,64)
        for (int i = tid; i < ND * 20; i += 256) {
            const int dxi = i / 20, j = i - dxi * 20;
            const int dx = 2 * dxi - 20, a = dx < 0 ? -dx : dx;
            if (j < a) {
                const int x = dx < 0 ? j : (NW - dx + j);
                ob[(size_t)dxi * HW + x] = 0.0f;
            }
        }
    }
}

// ---------- fallback (round-1 style) if ws is too small ----------------------
__global__ void __launch_bounds__(256, 2)
corr_fallback(const float* __restrict__ in1, const float* __restrict__ in2,
              float* __restrict__ out) {
    __shared__ unsigned short s1[ROW_ELEMS];
    __shared__ unsigned short s2[ROW_ELEMS];
    const int tid = threadIdx.x;
    const int b = blockIdx.x / NH, y = blockIdx.x % NH;
    const int lane = tid & 63, wave = tid >> 6;
    const int m_lo = lane & 15, quad = lane >> 4;
    const int asub = wave >> 1, bsub = wave & 1;
    {
        const int x = tid & 63, g0 = tid >> 6;
        const float* p = in1 + ((size_t)b * NC * NH + y) * NW + x;
        for (int i = 0; i < 8; ++i) {
            const int chunk = g0 * 8 + i;
            bf16x8 v = load_pack8(p, chunk * 8);
            *(bf16x8*)&s1[sw_addr(x, chunk)] = v;
        }
    }
    __syncthreads();
    bf16x8 afrag[2][8];
    for (int mm = 0; mm < 2; ++mm) {
        const int x = 32 * asub + 16 * mm + m_lo;
        for (int kb = 0; kb < 8; ++kb)
            afrag[mm][kb] = *(const bf16x8*)&s1[sw_addr(x, 4 * kb + quad)];
    }
    const float scale = 1.0f / 256.0f;
    for (int dyi = 0; dyi < ND; ++dyi) {
        const int ys = y + 2 * dyi - 20;
        float* ob = out + (((size_t)b * (ND * ND) + (size_t)dyi * ND) * NH + y) * NW;
        if ((unsigned)ys >= (unsigned)NH) {
            for (int i = tid; i < ND * NW; i += 256)
                ob[(size_t)(i >> 6) * HW + (i & 63)] = 0.0f;
            continue;
        }
        __syncthreads();
        {
            const int x = tid & 63, g0 = tid >> 6;
            const float* p = in2 + ((size_t)b * NC * NH + ys) * NW + x;
            for (int i = 0; i < 8; ++i) {
                const int chunk = g0 * 8 + i;
                bf16x8 v = load_pack8(p, chunk * 8);
                *(bf16x8*)&s2[sw_addr(x, chunk)] = v;
            }
        }
        __syncthreads();
        f32x4 acc[2][2];
        for (int mm = 0; mm < 2; ++mm)
            for (int nn = 0; nn < 2; ++nn) acc[mm][nn] = (f32x4){0.f, 0.f, 0.f, 0.f};
        for (int nn = 0; nn < 2; ++nn) {
            const int xpp = 32 * bsub + 16 * nn + m_lo;
            for (int kb = 0; kb < 8; ++kb) {
                bf16x8 bfrag = *(const bf16x8*)&s2[sw_addr(xpp, 4 * kb + quad)];
                acc[0][nn] = __builtin_amdgcn_mfma_f32_16x16x32_bf16(afrag[0][kb], bfrag, acc[0][nn], 0, 0, 0);
                acc[1][nn] = __builtin_amdgcn_mfma_f32_16x16x32_bf16(afrag[1][kb], bfrag, acc[1][nn], 0, 0, 0);
            }
        }
        for (int mm = 0; mm < 2; ++mm)
            for (int nn = 0; nn < 2; ++nn) {
                const int xb = 32 * asub + 16 * mm + 4 * quad;
                const int xpp = 32 * bsub + 16 * nn + m_lo;
                for (int r = 0; r < 4; ++r) {
                    const int x = xb + r, d = xpp - x;
                    if (d >= -20 && d <= 20 && !(d & 1))
                        ob[(size_t)((d + 20) >> 1) * HW + x] = acc[mm][nn][r] * scale;
                }
            }
        for (int i = tid; i < ND * 20; i += 256) {
            const int dxi = i / 20, j = i - dxi * 20;
            const int dx = 2 * dxi - 20, a = dx < 0 ? -dx : dx;
            if (j < a) {
                const int x = dx < 0 ? j : (NW - dx + j);
                ob[(size_t)dxi * HW + x] = 0.0f;
            }
        }
    }
}

extern "C" void kernel_launch(void* const* d_in, const int* in_sizes, int n_in,
                              void* d_out, int out_size, void* d_ws, size_t ws_size,
                              hipStream_t stream) {
    const float* in1 = (const float*)d_in[0];
    const float* in2 = (const float*)d_in[1];
    float* out = (float*)d_out;
    const size_t need = (size_t)NB * NH * ROW_ELEMS * sizeof(unsigned short);
    if (ws_size >= need) {
        convert_in2<<<dim3(NB * NH), dim3(256), 0, stream>>>(in2, (unsigned short*)d_ws);
        corr_main<<<dim3(NB * NH), dim3(256), 0, stream>>>(in1, (const unsigned short*)d_ws, out);
    } else {
        corr_fallback<<<dim3(NB * NH), dim3(256), 0, stream>>>(in1, in2, out);
    }
}

// Round 4
// 211.545 us; speedup vs baseline: 1.2000x; 1.2000x over previous
//
#include <hip/hip_runtime.h>
#include <stdint.h>

#define NB 16
#define NC 256
#define NH 48
#define NW 64
#define ND 21
#define HW (NH * NW)
#define ROW_ELEMS (NW * NC)   // one (b,y) row as [x][c] bf16: 16384 elems = 32KB
#define SOUT_LD (NW + 1)      // padded leading dim for epilogue buffer

typedef __bf16 bf16x8 __attribute__((ext_vector_type(8)));
typedef float f32x4 __attribute__((ext_vector_type(4)));

// row layout: [x][c] bf16, c in 16B chunks of 8; low-3 chunk bits XOR (x&7).
// 512B per x. ds_read_b128 / ds_write_b128 on this layout are conflict-free.
__device__ __forceinline__ int sw_addr(int x, int chunk) {
    int cs = (chunk & ~7) | ((chunk ^ x) & 7);
    return x * 256 + (cs << 3);
}

// read 8 consecutive c (coalesced across x-lanes) -> packed bf16x8
__device__ __forceinline__ bf16x8 load_pack8(const float* __restrict__ p, int cbase) {
    bf16x8 v;
#pragma unroll
    for (int j = 0; j < 8; ++j)
        v[j] = (__bf16)p[(size_t)(cbase + j) * HW];
    return v;
}

// ---------- pre-pass: in2 fp32 [b][c][h][w] -> ws bf16 rows (swizzle baked) --
__global__ void __launch_bounds__(256, 4)
convert_in2(const float* __restrict__ in2, unsigned short* __restrict__ ws) {
    __shared__ unsigned short s[ROW_ELEMS];
    const int tid = threadIdx.x;
    const int b = blockIdx.x / NH, y = blockIdx.x % NH;
    const int x = tid & 63, g0 = tid >> 6;
    const float* p = in2 + ((size_t)b * NC * NH + y) * NW + x;
#pragma unroll
    for (int i = 0; i < 8; ++i) {
        const int chunk = g0 * 8 + i;                  // c = chunk*8 .. +7
        bf16x8 v = load_pack8(p, chunk * 8);
        *(bf16x8*)&s[sw_addr(x, chunk)] = v;           // b128, conflict-free
    }
    __syncthreads();
    unsigned short* wr = ws + ((size_t)b * NH + y) * ROW_ELEMS;
#pragma unroll
    for (int i = 0; i < 8; ++i) {
        const int e = (i * 256 + tid) * 8;
        *(bf16x8*)(wr + e) = *(const bf16x8*)(s + e);  // linear, coalesced
    }
}

// ---------- main: block per (b,y); wave = M64 x N16; coalesced epilogue -----
__global__ void __launch_bounds__(256, 2)
corr_main(const float* __restrict__ in1, const unsigned short* __restrict__ ws,
          float* __restrict__ out) {
    __shared__ unsigned short s1[ROW_ELEMS];    // 32KB in1 row (resident)
    __shared__ float sout[ND * SOUT_LD];        // 5.4KB epilogue transpose buf
    const int tid  = threadIdx.x;
    const int b    = blockIdx.x / NH, y = blockIdx.x % NH;
    const int lane = tid & 63, wave = tid >> 6;
    const int m_lo = lane & 15, quad = lane >> 4;

    // ---- stage in1 row (register-packed, conflict-free b128 writes)
    {
        const int x = tid & 63, g0 = tid >> 6;
        const float* p = in1 + ((size_t)b * NC * NH + y) * NW + x;
#pragma unroll
        for (int i = 0; i < 8; ++i) {
            const int chunk = g0 * 8 + i;
            bf16x8 v = load_pack8(p, chunk * 8);
            *(bf16x8*)&s1[sw_addr(x, chunk)] = v;
        }
    }
    // zero the epilogue buffer while staging lands
    for (int i = tid; i < ND * SOUT_LD; i += 256) sout[i] = 0.0f;
    __syncthreads();

    // ---- cache A for all 4 M-tiles: A[m=lane&15][k=quad*8+j]
    bf16x8 afrag[4][8];
#pragma unroll
    for (int mm = 0; mm < 4; ++mm) {
        const int x = 16 * mm + m_lo;
#pragma unroll
        for (int kb = 0; kb < 8; ++kb)
            afrag[mm][kb] = *(const bf16x8*)&s1[sw_addr(x, 4 * kb + quad)];
    }

    // ---- zero invalid dy planes (coalesced, nontemporal)
    const int d0 = (y >= 20) ? 0 : (21 - y) >> 1;
    const int d1 = min(20, (67 - y) >> 1);
    float* outbase = out + (((size_t)b * (ND * ND)) * NH + (size_t)y) * NW;
    for (int dyi = 0; dyi < ND; ++dyi) {
        if (dyi >= d0 && dyi <= d1) continue;
        float* ob = outbase + (size_t)dyi * ND * HW;
        for (int i = tid; i < ND * NW; i += 256)
            __builtin_nontemporal_store(0.0f, &ob[(size_t)(i >> 6) * HW + (i & 63)]);
    }

    const unsigned short* wsb = ws + (size_t)b * NH * ROW_ELEMS;
    const float scale = 1.0f / 256.0f;
    const int xp = 16 * wave + m_lo;  // this lane's B column (x')

    auto load_b = [&](bf16x8 (&bf)[8], int dyi) {
        const unsigned short* row = wsb + (size_t)(y - 20 + 2 * dyi) * ROW_ELEMS;
#pragma unroll
        for (int kb = 0; kb < 8; ++kb)
            bf[kb] = *(const bf16x8*)&row[sw_addr(xp, 4 * kb + quad)];
    };

    // one dy step: compute with bc, prefetch dy+1 into bn, coalesced epilogue
    auto step = [&](bf16x8 (&bc)[8], bf16x8 (&bn)[8], int dyi) {
        f32x4 acc[4];
#pragma unroll
        for (int mm = 0; mm < 4; ++mm) acc[mm] = (f32x4){0.f, 0.f, 0.f, 0.f};
#pragma unroll
        for (int kb = 0; kb < 8; ++kb) {
            acc[0] = __builtin_amdgcn_mfma_f32_16x16x32_bf16(afrag[0][kb], bc[kb], acc[0], 0, 0, 0);
            acc[1] = __builtin_amdgcn_mfma_f32_16x16x32_bf16(afrag[1][kb], bc[kb], acc[1], 0, 0, 0);
            acc[2] = __builtin_amdgcn_mfma_f32_16x16x32_bf16(afrag[2][kb], bc[kb], acc[2], 0, 0, 0);
            acc[3] = __builtin_amdgcn_mfma_f32_16x16x32_bf16(afrag[3][kb], bc[kb], acc[3], 0, 0, 0);
        }
        if (dyi < d1) load_b(bn, dyi + 1);  // latency hides under epilogue

        // scatter band entries into LDS: row = 16*mm+4*quad+r (=x), col = xp
#pragma unroll
        for (int mm = 0; mm < 4; ++mm) {
            const int xb = 16 * mm + 4 * quad;
#pragma unroll
            for (int r = 0; r < 4; ++r) {
                const int x = xb + r;
                const int d = xp - x;
                if (d >= -20 && d <= 20 && !(d & 1))
                    sout[((d + 20) >> 1) * SOUT_LD + x] = acc[mm][r];
            }
        }
        __syncthreads();
        // coalesced plane store + re-zero for next dy
        float* ob = outbase + (size_t)dyi * ND * HW;
        for (int i = tid; i < ND * NW; i += 256) {
            const int pl = i >> 6, x = i & 63;
            float v = sout[pl * SOUT_LD + x];
            __builtin_nontemporal_store(v * scale, &ob[(size_t)pl * HW + x]);
            sout[pl * SOUT_LD + x] = 0.0f;
        }
        __syncthreads();
    };

    bf16x8 bfA[8], bfB[8];
    load_b(bfA, d0);
    int dyi = d0;
    while (true) {
        step(bfA, bfB, dyi);
        if (++dyi > d1) break;
        step(bfB, bfA, dyi);
        if (++dyi > d1) break;
    }
}

// ---------- fallback (round-1 style) if ws is too small ----------------------
__global__ void __launch_bounds__(256, 2)
corr_fallback(const float* __restrict__ in1, const float* __restrict__ in2,
              float* __restrict__ out) {
    __shared__ unsigned short s1[ROW_ELEMS];
    __shared__ unsigned short s2[ROW_ELEMS];
    const int tid = threadIdx.x;
    const int b = blockIdx.x / NH, y = blockIdx.x % NH;
    const int lane = tid & 63, wave = tid >> 6;
    const int m_lo = lane & 15, quad = lane >> 4;
    const int asub = wave >> 1, bsub = wave & 1;
    {
        const int x = tid & 63, g0 = tid >> 6;
        const float* p = in1 + ((size_t)b * NC * NH + y) * NW + x;
        for (int i = 0; i < 8; ++i) {
            const int chunk = g0 * 8 + i;
            bf16x8 v = load_pack8(p, chunk * 8);
            *(bf16x8*)&s1[sw_addr(x, chunk)] = v;
        }
    }
    __syncthreads();
    bf16x8 afrag[2][8];
    for (int mm = 0; mm < 2; ++mm) {
        const int x = 32 * asub + 16 * mm + m_lo;
        for (int kb = 0; kb < 8; ++kb)
            afrag[mm][kb] = *(const bf16x8*)&s1[sw_addr(x, 4 * kb + quad)];
    }
    const float scale = 1.0f / 256.0f;
    for (int dyi = 0; dyi < ND; ++dyi) {
        const int ys = y + 2 * dyi - 20;
        float* ob = out + (((size_t)b * (ND * ND) + (size_t)dyi * ND) * NH + y) * NW;
        if ((unsigned)ys >= (unsigned)NH) {
            for (int i = tid; i < ND * NW; i += 256)
                ob[(size_t)(i >> 6) * HW + (i & 63)] = 0.0f;
            continue;
        }
        __syncthreads();
        {
            const int x = tid & 63, g0 = tid >> 6;
            const float* p = in2 + ((size_t)b * NC * NH + ys) * NW + x;
            for (int i = 0; i < 8; ++i) {
                const int chunk = g0 * 8 + i;
                bf16x8 v = load_pack8(p, chunk * 8);
                *(bf16x8*)&s2[sw_addr(x, chunk)] = v;
            }
        }
        __syncthreads();
        f32x4 acc[2][2];
        for (int mm = 0; mm < 2; ++mm)
            for (int nn = 0; nn < 2; ++nn) acc[mm][nn] = (f32x4){0.f, 0.f, 0.f, 0.f};
        for (int nn = 0; nn < 2; ++nn) {
            const int xpp = 32 * bsub + 16 * nn + m_lo;
            for (int kb = 0; kb < 8; ++kb) {
                bf16x8 bfrag = *(const bf16x8*)&s2[sw_addr(xpp, 4 * kb + quad)];
                acc[0][nn] = __builtin_amdgcn_mfma_f32_16x16x32_bf16(afrag[0][kb], bfrag, acc[0][nn], 0, 0, 0);
                acc[1][nn] = __builtin_amdgcn_mfma_f32_16x16x32_bf16(afrag[1][kb], bfrag, acc[1][nn], 0, 0, 0);
            }
        }
        for (int mm = 0; mm < 2; ++mm)
            for (int nn = 0; nn < 2; ++nn) {
                const int xb = 32 * asub + 16 * mm + 4 * quad;
                const int xpp = 32 * bsub + 16 * nn + m_lo;
                for (int r = 0; r < 4; ++r) {
                    const int x = xb + r, d = xpp - x;
                    if (d >= -20 && d <= 20 && !(d & 1))
                        ob[(size_t)((d + 20) >> 1) * HW + x] = acc[mm][nn][r] * scale;
                }
            }
        for (int i = tid; i < ND * 20; i += 256) {
            const int dxi = i / 20, j = i - dxi * 20;
            const int dx = 2 * dxi - 20, a = dx < 0 ? -dx : dx;
            if (j < a) {
                const int x = dx < 0 ? j : (NW - dx + j);
                ob[(size_t)dxi * HW + x] = 0.0f;
            }
        }
    }
}

extern "C" void kernel_launch(void* const* d_in, const int* in_sizes, int n_in,
                              void* d_out, int out_size, void* d_ws, size_t ws_size,
                              hipStream_t stream) {
    const float* in1 = (const float*)d_in[0];
    const float* in2 = (const float*)d_in[1];
    float* out = (float*)d_out;
    const size_t need = (size_t)NB * NH * ROW_ELEMS * sizeof(unsigned short);
    if (ws_size >= need) {
        convert_in2<<<dim3(NB * NH), dim3(256), 0, stream>>>(in2, (unsigned short*)d_ws);
        corr_main<<<dim3(NB * NH), dim3(256), 0, stream>>>(in1, (const unsigned short*)d_ws, out);
    } else {
        corr_fallback<<<dim3(NB * NH), dim3(256), 0, stream>>>(in1, in2, out);
    }
}